// Round 8
// baseline (842.837 us; speedup 1.0000x reference)
//
#include <hip/hip_runtime.h>
#include <hip/hip_bf16.h>

// RiemannianGraph_HRSNN, MFMA version. B=2048, T=15, N=64. All I/O f32.
// R7 post-mortem: R6's d_ws-overflow theory refuted (R7 used exactly 32 MiB,
// still failed ~1.x). Common cause across R6/R7 = the R6 main-kernel change
// set; prime suspect is the XOR swizzle (thrice paper-verified but failing).
// R8: revert ALL swizzled indexing to the R5-proven forms; fix the phase-C
// 4-way bank conflict instead with a transposed copy S1T[f][n] (stride 65,
// odd -> bS banks = c+8q+j mod 32 = 2 lanes/bank = free). Keep
// launch_bounds(512,4) (occupancy-only) and the R7 decoder (LDS-staged W1,
// MFMA GEMM). If this fails ~1.x the decoder is convicted.
//
// Math:
//   L 3-part x S1(exact)            -> 2^-27
//   M 3-part x Wg2 3-part (6 terms) -> ~2^-24
//   S1(exact) x Ws2 2-part          -> 2^-18 (no threshold downstream)
//   L 3-part x Xt 2-part (3 terms)  -> ~2^-17
//   dp 2-part x W1 2-part (3 terms) -> ~2^-16
// MFMA layouts: A[row=lane&15][k=8*(lane>>4)+j], B[k=8q+j][col=lane&15],
// C/D[row=4*(lane>>4)+reg][col=lane&15].

typedef __attribute__((ext_vector_type(8))) short s16x8;
typedef __attribute__((ext_vector_type(4))) float f32x4;
#define MFMA16(a, b, c) __builtin_amdgcn_mfma_f32_16x16x32_bf16(a, b, c, 0, 0, 0)

__device__ __forceinline__ short f2bs(float x) {
  union { __hip_bfloat16 h; short s; } u; u.h = __float2bfloat16(x); return u.s;
}
__device__ __forceinline__ float bs2f(short s) {
  union { short s; __hip_bfloat16 h; } u; u.s = s; return __bfloat162float(u.h);
}

#define LIF_STEP(mem, beta, thr, cur, spksum)                \
  {                                                          \
    float r_ = ((mem) > (thr)) ? (thr) : 0.0f;               \
    (mem) = (beta) * (mem) + (cur) - r_;                     \
    (spksum) += (((mem) - (thr)) > 0.0f) ? 1.0f : 0.0f;      \
  }

#define LFS 68      // Lf row stride (f32 words)
#define RS  36      // S1row / Mrow row stride
#define TS  65      // S1T row stride (odd -> conflict-free column pattern)

__global__ __launch_bounds__(512, 4)
void hrsnn_main(const float* __restrict__ Lg,  const float* __restrict__ Xg,
                const float* __restrict__ Wp,  const float* __restrict__ bp,
                const float* __restrict__ Wg1, const float* __restrict__ bg1,
                const float* __restrict__ Ws1, const float* __restrict__ bs1,
                const float* __restrict__ Wg2, const float* __restrict__ bg2,
                const float* __restrict__ Ws2, const float* __restrict__ bs2,
                unsigned int* __restrict__ dp_out)
{
  // UBUF: union of Lf[64][68] (init only, 4352) with S1row[64][36]+Mrow[64][36]
  __shared__ __align__(16) float UBUF[4608];
  float* const Lf    = UBUF;          // init only
  float* const S1row = UBUF;          // [64][RS] plain row-major
  float* const Mrow  = UBUF + 2304;   // [64][RS] plain row-major
  __shared__ __align__(16) float S1T[32 * TS];          // S1 transposed [f][n]
  __shared__ __align__(16) short WgF[4 * 3 * 64 * 8];   // Wg2 frags [tile][part][lane][8]
  __shared__ __align__(16) unsigned int XtHL[960];      // packed (hi<<16|lo) bf16 of Xt
  __shared__ __align__(16) float Xtf[960];
  __shared__ float LxS[64], LsumS[64];
  __shared__ float u1A[32], cb1A[32], us1v[32], cs1v[32];
  __shared__ float u2gA[64], c2gA[64], u2sA[64], cs2A[64];

  const int tid = threadIdx.x;
  const int b = blockIdx.x;
  const int l = tid & 63, w = tid >> 6;
  const int p = w >> 1, h = w & 1;          // row-stripe / col-half
  const int q = l >> 4, c = l & 15;
  const int R = 16 * p;

  // ================= init 1: stage Lf, Xt (split), small weight folds ========
  const float* Lb = Lg + (size_t)b * 4096;
#pragma unroll
  for (int k = 0; k < 2; k++) {
    const int i4 = tid + 512 * k;                 // float4 index in [0,1024)
    const float4 v = *(const float4*)&Lb[i4 * 4];
    *(float4*)&Lf[(i4 >> 4) * LFS + (i4 & 15) * 4] = v;
  }
  const float* Xb = Xg + (size_t)b * 960;
  for (int i = tid; i < 960; i += 512) {
    const float x = Xb[i];
    const short hs = f2bs(x);
    const short ls = f2bs(x - bs2f(hs));
    XtHL[i] = ((unsigned int)(unsigned short)hs << 16) | (unsigned short)ls;
    Xtf[i] = x;
  }
  if (tid < 32) {
    const int f = tid;
    float a = 0.f, bb = 0.f, cc = 0.f, d = 0.f;
    for (int k = 0; k < 16; k++) {
      const float wp = Wp[k], bpv = bp[k];
      const float wg = Wg1[k * 32 + f], ws = Ws1[k * 32 + f];
      a += wp * wg; bb += bpv * wg;
      cc += wp * ws; d += bpv * ws;
    }
    u1A[f] = a; cb1A[f] = bb;
    us1v[f] = cc; cs1v[f] = d + bs1[f];
  }
  __syncthreads();

  // ================= init 2: Lsum, L A-frags, WgF, Ws2 frags ================
  {
    const int n = tid >> 3, o = tid & 7;
    const float4 a4 = *(const float4*)&Lf[n * LFS + 8 * o];
    const float4 b4 = *(const float4*)&Lf[n * LFS + 8 * o + 4];
    float ps = a4.x + a4.y + a4.z + a4.w + b4.x + b4.y + b4.z + b4.w;
    ps += __shfl_xor(ps, 1, 64);
    ps += __shfl_xor(ps, 2, 64);
    ps += __shfl_xor(ps, 4, 64);
    if (o == 0) LsumS[n] = ps;
  }
  // L A-frags: 3 parts x 2 K-slices (K=64)
  s16x8 Lh[2], Lm[2], Ll[2];
#pragma unroll
  for (int s = 0; s < 2; s++) {
    const float* rp = &Lf[(R + c) * LFS + 32 * s + 8 * q];
    const float4 v0 = *(const float4*)rp;
    const float4 v1 = *(const float4*)(rp + 4);
    float v[8] = {v0.x, v0.y, v0.z, v0.w, v1.x, v1.y, v1.z, v1.w};
#pragma unroll
    for (int j = 0; j < 8; j++) {
      const short hh = f2bs(v[j]);       const float r1 = v[j] - bs2f(hh);
      const short mm = f2bs(r1);         const float r2 = r1 - bs2f(mm);
      Lh[s][j] = hh; Lm[s][j] = mm; Ll[s][j] = f2bs(r2);
    }
  }
  // Wg2 fragment store: wave w builds tile tt=w&3; w<4 -> parts 0,1; w>=4 -> part 2
  {
    const int tt = w & 3;
    float v[8];
#pragma unroll
    for (int j = 0; j < 8; j++) v[j] = Wg2[(8 * q + j) * 64 + 16 * tt + c];
    if (w < 4) {
      s16x8 fh, fm;
#pragma unroll
      for (int j = 0; j < 8; j++) {
        const short hh = f2bs(v[j]);
        fh[j] = hh; fm[j] = f2bs(v[j] - bs2f(hh));
      }
      *(s16x8*)&WgF[((tt * 3 + 0) * 64 + l) * 8] = fh;
      *(s16x8*)&WgF[((tt * 3 + 1) * 64 + l) * 8] = fm;
    } else {
      s16x8 fl;
#pragma unroll
      for (int j = 0; j < 8; j++) {
        const short hh = f2bs(v[j]);     const float r1 = v[j] - bs2f(hh);
        const short mm = f2bs(r1);       const float r2 = r1 - bs2f(mm);
        fl[j] = f2bs(r2);
      }
      *(s16x8*)&WgF[((tt * 3 + 2) * 64 + l) * 8] = fl;
    }
  }
  // Ws2 frags (2-part) for this wave's two g-tiles, in registers
  s16x8 WsH[2], WsL[2];
#pragma unroll
  for (int i = 0; i < 2; i++) {
    const int g0 = 32 * h + 16 * i;
#pragma unroll
    for (int j = 0; j < 8; j++) {
      const float x = Ws2[(8 * q + j) * 64 + g0 + c];
      const short hh = f2bs(x);
      WsH[i][j] = hh; WsL[i][j] = f2bs(x - bs2f(hh));
    }
  }
  __syncthreads();

  // ================= init 3: layer-2 derived vectors =========================
  if (tid < 64) {
    const int g = tid;
    float a = 0.f, bb = 0.f, cc = 0.f, d = 0.f;
    for (int f = 0; f < 32; f++) {
      const float wg = Wg2[f * 64 + g], ws = Ws2[f * 64 + g];
      a += us1v[f] * wg; bb += cs1v[f] * wg;
      cc += us1v[f] * ws; d += cs1v[f] * ws;
    }
    u2gA[g] = a; c2gA[g] = bb; u2sA[g] = cc; cs2A[g] = d + bs2[g];
  }
  __syncthreads();

  // ================= init 4: per-lane constants (registers only) =============
  float u2g2[2], u2s2[2], cs22[2], c2c[2][4];
#pragma unroll
  for (int i = 0; i < 2; i++) {
    const int g = 32 * h + 16 * i + c;
    u2g2[i] = u2gA[g]; u2s2[i] = u2sA[g]; cs22[i] = cs2A[g];
    const float cg = c2gA[g], bg = bg2[g];
#pragma unroll
    for (int r = 0; r < 4; r++) c2c[i][r] = LsumS[R + 4 * q + r] * cg + bg;
  }
  // LIF-1 mapping: f = tid&31, nb = tid>>5, cells n = nb + 16j
  const int f1 = tid & 31, nb = tid >> 5;
  const float u1f = u1A[f1];
  float k1c[4];
  {
    const float cb = cb1A[f1], bg = bg1[f1];
#pragma unroll
    for (int j = 0; j < 4; j++) k1c[j] = LsumS[nb + 16 * j] * cb + bg;
  }

  // ================= state registers =========================================
  float m1a[4], m1n[4], m1m[4];
#pragma unroll
  for (int j = 0; j < 4; j++) { m1a[j] = 0.f; m1n[j] = 0.f; m1m[j] = 0.f; }
  float m2a[2][4], m2n[2][4], m2m[2][4], mli[2][4], dpa[2][4];
#pragma unroll
  for (int i = 0; i < 2; i++)
#pragma unroll
    for (int r = 0; r < 4; r++) {
      m2a[i][r] = 0.f; m2n[i][r] = 0.f; m2m[i][r] = 0.f;
      mli[i][r] = 0.f; dpa[i][r] = 0.f;
    }

  const f32x4 fz = {0.f, 0.f, 0.f, 0.f};
  __syncthreads();   // Lf dead; UBUF becomes S1row/Mrow

  // ================= time loop: 3 barriers/step ==============================
  // Barrier safety with no end-of-step barrier: D(t) reads Mrow; C(t+1)
  // writes Mrow only after alpha(t+1)+beta(t+1). Same two-barrier separation
  // covers C(t)'s S1row/S1T reads vs B(t+1)'s writes and B(t)'s LxS reads vs
  // A(t+1)'s writes. (Structure identical to R5, which passed.)
  for (int t = 0; t < 15; t++) {
    // ---- phase A: Lx = L@Xt via MFMA broadcast (all B-cols = Xt) ----
    f32x4 lx = fz;
#pragma unroll
    for (int s = 0; s < 2; s++) {
      const unsigned int* xw = &XtHL[t * 64 + 32 * s + 8 * q];
      const uint4 w0 = *(const uint4*)xw;
      const uint4 w1 = *(const uint4*)(xw + 4);
      unsigned int wv[8] = {w0.x, w0.y, w0.z, w0.w, w1.x, w1.y, w1.z, w1.w};
      s16x8 bh, bl;
#pragma unroll
      for (int j = 0; j < 8; j++) {
        bh[j] = (short)(wv[j] >> 16);
        bl[j] = (short)(wv[j] & 0xffff);
      }
      lx = MFMA16(Lh[s], bh, lx);
      lx = MFMA16(Lm[s], bh, lx);
      lx = MFMA16(Lh[s], bl, lx);
    }
    if (h == 0 && c == 0) {
#pragma unroll
      for (int r = 0; r < 4; r++) LxS[R + 4 * q + r] = lx[r];
    }
    __syncthreads();   // alpha

    // ---- phase B: layer-1 LIF -> S1row (plain) + S1T (transposed) ----
#pragma unroll
    for (int j = 0; j < 4; j++) {
      const int n = nb + 16 * j;
      const float cur = LxS[n] * u1f + k1c[j];
      float ss = 0.f;
      LIF_STEP(m1a[j], 0.8f, 0.8f, cur, ss);
      LIF_STEP(m1n[j], 0.9f, 1.0f, cur, ss);
      LIF_STEP(m1m[j], 0.95f, 1.5f, cur, ss);
      S1row[n * RS + f1] = ss;
      S1T[f1 * TS + n] = ss;
    }
    __syncthreads();   // beta

    // ---- phase C: M = L@S1 (3-part L), spk2d = S1@Ws2 (2-part W) ----
    f32x4 macc = fz;
#pragma unroll
    for (int s = 0; s < 2; s++) {
      s16x8 bS;
#pragma unroll
      for (int j = 0; j < 8; j++)
        bS[j] = f2bs(S1T[(16 * h + c) * TS + 32 * s + 8 * q + j]);
      macc = MFMA16(Lh[s], bS, macc);
      macc = MFMA16(Lm[s], bS, macc);
      macc = MFMA16(Ll[s], bS, macc);
    }
#pragma unroll
    for (int r = 0; r < 4; r++) Mrow[(R + 4 * q + r) * RS + 16 * h + c] = macc[r];

    f32x4 sacc[2];
    {
      const float* rp = &S1row[(R + c) * RS + 8 * q];
      const float4 v0 = *(const float4*)rp;
      const float4 v1 = *(const float4*)(rp + 4);
      const float v[8] = {v0.x, v0.y, v0.z, v0.w, v1.x, v1.y, v1.z, v1.w};
      s16x8 aS;
#pragma unroll
      for (int j = 0; j < 8; j++) aS[j] = f2bs(v[j]);
#pragma unroll
      for (int i = 0; i < 2; i++) {
        sacc[i] = MFMA16(aS, WsH[i], fz);
        sacc[i] = MFMA16(aS, WsL[i], sacc[i]);
      }
    }
    __syncthreads();   // gamma

    // ---- phase D: cur2 = M@Wg2 (6-term) + LIF-2 (all in registers) ----
    s16x8 aMh, aMm, aMl;
    {
      const float* rp = &Mrow[(R + c) * RS + 8 * q];
      const float4 v0 = *(const float4*)rp;
      const float4 v1 = *(const float4*)(rp + 4);
      const float v[8] = {v0.x, v0.y, v0.z, v0.w, v1.x, v1.y, v1.z, v1.w};
#pragma unroll
      for (int j = 0; j < 8; j++) {
        const short hh = f2bs(v[j]);     const float r1 = v[j] - bs2f(hh);
        const short mm = f2bs(r1);       const float r2 = r1 - bs2f(mm);
        aMh[j] = hh; aMm[j] = mm; aMl[j] = f2bs(r2);
      }
    }
    float xtn[4];
#pragma unroll
    for (int r = 0; r < 4; r++) xtn[r] = Xtf[t * 64 + R + 4 * q + r];

#pragma unroll
    for (int i = 0; i < 2; i++) {
      const int tt = 2 * h + i;
      const s16x8 bGh = *(const s16x8*)&WgF[((tt * 3 + 0) * 64 + l) * 8];
      const s16x8 bGm = *(const s16x8*)&WgF[((tt * 3 + 1) * 64 + l) * 8];
      const s16x8 bGl = *(const s16x8*)&WgF[((tt * 3 + 2) * 64 + l) * 8];
      f32x4 cacc = fz;
      cacc = MFMA16(aMh, bGh, cacc);
      cacc = MFMA16(aMh, bGm, cacc);
      cacc = MFMA16(aMm, bGh, cacc);
      cacc = MFMA16(aMh, bGl, cacc);
      cacc = MFMA16(aMm, bGm, cacc);
      cacc = MFMA16(aMl, bGh, cacc);
#pragma unroll
      for (int r = 0; r < 4; r++) {
        const float cur2 = cacc[r] + lx[r] * u2g2[i] + c2c[i][r];
        float ss = 0.f;
        LIF_STEP(m2a[i][r], 0.8f, 0.8f, cur2, ss);
        LIF_STEP(m2n[i][r], 0.9f, 1.0f, cur2, ss);
        LIF_STEP(m2m[i][r], 0.95f, 1.5f, cur2, ss);
        const float spk2 = ss + sacc[i][r] + xtn[r] * u2s2[i] + cs22[i];
        mli[i][r] = 0.9f * mli[i][r] + spk2;
      }
    }
    if (t < 5) {
#pragma unroll
      for (int i = 0; i < 2; i++)
#pragma unroll
        for (int r = 0; r < 4; r++) dpa[i][r] -= mli[i][r];
    } else if (t >= 10) {
#pragma unroll
      for (int i = 0; i < 2; i++)
#pragma unroll
        for (int r = 0; r < 4; r++) dpa[i][r] += mli[i][r];
    }
    // no end-of-step barrier (see proof above)
  }

  // ---- dp_feat = (sum_last5 - sum_first5)/5, packed split-bf16 ----
  unsigned int* dpb = dp_out + (size_t)b * 4096;
#pragma unroll
  for (int i = 0; i < 2; i++) {
    const int g = 32 * h + 16 * i + c;
#pragma unroll
    for (int r = 0; r < 4; r++) {
      const int n = R + 4 * q + r;
      const float v = dpa[i][r] * 0.2f;
      const short hh = f2bs(v);
      const short ll = f2bs(v - bs2f(hh));
      dpb[n * 64 + g] = ((unsigned int)(unsigned short)hh << 16) | (unsigned short)ll;
    }
  }
}

// Decoder: out = relu(dp @ W1 + b1) @ W2 + b2 as an MFMA GEMM.
// grid 256 = 128 batch-tiles x 2 col-halves; 256 thr = 4 waves = 4 col-tiles.
// W1 staged per 128-row chunk into LDS as packed split-bf16 (stride 65).
// A from packed dp (uint4). Dual accumulators break the MFMA chain.
// Epilogue: block reduces its 64 cols via LDS, atomicAdds into zeroed out.
__global__ __launch_bounds__(256, 4)
void hrsnn_decoder(const unsigned int* __restrict__ dpq,
                   const float* __restrict__ W1,
                   const float* __restrict__ b1, const float* __restrict__ W2,
                   const float* __restrict__ b2, float* __restrict__ out)
{
  __shared__ __align__(16) unsigned int T[128][65];   // packed split W1 chunk (33 KB)
  __shared__ __align__(16) float Hl[16][68];
  const int tid = threadIdx.x;
  const int l = tid & 63, tt = tid >> 6;       // 4 waves = 4 col tiles
  const int q = l >> 4, c = l & 15;
  const int bt = blockIdx.x >> 1, ch = blockIdx.x & 1;
  const int colg = ch * 64 + tt * 16 + c;      // global col in [0,128)

  const unsigned int* ar = dpq + (size_t)(bt * 16 + c) * 4096 + 8 * q;
  const float* wbase = W1 + ch * 64;           // this block's 64-col half

  const f32x4 fz = {0.f, 0.f, 0.f, 0.f};
  f32x4 acc0 = fz, acc1 = fz;
  for (int kc = 0; kc < 32; kc++) {            // K-chunks of 128 rows
    __syncthreads();                           // protect T reuse
#pragma unroll
    for (int u = 0; u < 8; u++) {
      const int i4 = tid + 256 * u;            // float4 idx in [0,2048)
      const int kk = i4 >> 4, c4 = (i4 & 15) * 4;
      const float4 v = *(const float4*)&wbase[(size_t)(kc * 128 + kk) * 128 + c4];
      const float vv[4] = {v.x, v.y, v.z, v.w};
#pragma unroll
      for (int e = 0; e < 4; e++) {
        const short hh = f2bs(vv[e]);
        const short ll = f2bs(vv[e] - bs2f(hh));
        T[kk][c4 + e] = ((unsigned int)(unsigned short)hh << 16) | (unsigned short)ll;
      }
    }
    __syncthreads();
#pragma unroll
    for (int sl = 0; sl < 4; sl++) {           // 4 K-slices of 32 per chunk
      const int s = 4 * kc + sl;
      const uint4 a0 = *(const uint4*)(ar + 32 * s);
      const uint4 a1 = *(const uint4*)(ar + 32 * s + 4);
      const unsigned int av[8] = {a0.x, a0.y, a0.z, a0.w, a1.x, a1.y, a1.z, a1.w};
      s16x8 Ah, Al, Bh, Bl;
#pragma unroll
      for (int j = 0; j < 8; j++) {
        Ah[j] = (short)(av[j] >> 16);
        Al[j] = (short)(av[j] & 0xffff);
        const unsigned int bw = T[32 * sl + 8 * q + j][16 * tt + c];
        Bh[j] = (short)(bw >> 16);
        Bl[j] = (short)(bw & 0xffff);
      }
      if (sl & 1) {
        acc1 = MFMA16(Ah, Bh, acc1);
        acc1 = MFMA16(Al, Bh, acc1);
        acc1 = MFMA16(Ah, Bl, acc1);
      } else {
        acc0 = MFMA16(Ah, Bh, acc0);
        acc0 = MFMA16(Al, Bh, acc0);
        acc0 = MFMA16(Ah, Bl, acc0);
      }
    }
  }

  const float bk = b1[colg];
#pragma unroll
  for (int r = 0; r < 4; r++) {
    const float hv = acc0[r] + acc1[r] + bk;
    Hl[4 * q + r][tt * 16 + c] = hv > 0.f ? hv : 0.f;
  }
  __syncthreads();

  if (tid < 64) {
    const int i = tid >> 2, o = tid & 3;
    float s = (ch == 0) ? b2[o] : 0.f;
    for (int cc = 0; cc < 64; cc++)
      s += Hl[i][cc] * W2[(ch * 64 + cc) * 4 + o];
    atomicAdd(&out[(size_t)(bt * 16 + i) * 4 + o], s);
  }
}

extern "C" void kernel_launch(void* const* d_in, const int* in_sizes, int n_in,
                              void* d_out, int out_size, void* d_ws, size_t ws_size,
                              hipStream_t stream)
{
  const float* Lg  = (const float*)d_in[0];
  const float* Xg  = (const float*)d_in[1];
  const float* Wp  = (const float*)d_in[2];
  const float* bp  = (const float*)d_in[3];
  const float* Wg1 = (const float*)d_in[4];
  const float* bg1 = (const float*)d_in[5];
  const float* Ws1 = (const float*)d_in[6];
  const float* bs1 = (const float*)d_in[7];
  const float* Wg2 = (const float*)d_in[8];
  const float* bg2 = (const float*)d_in[9];
  const float* Ws2 = (const float*)d_in[10];
  const float* bs2 = (const float*)d_in[11];
  const float* W1  = (const float*)d_in[12];
  const float* b1  = (const float*)d_in[13];
  const float* W2  = (const float*)d_in[14];
  const float* b2  = (const float*)d_in[15];

  unsigned int* dpq = (unsigned int*)d_ws;  // 2048*4096 packed uint = 32 MiB (total ws use)
  float* out = (float*)d_out;               // [2048, 4] f32

  hipLaunchKernelGGL(hrsnn_main, dim3(2048), dim3(512), 0, stream,
                     Lg, Xg, Wp, bp, Wg1, bg1, Ws1, bs1, Wg2, bg2, Ws2, bs2, dpq);
  hipMemsetAsync(d_out, 0, (size_t)out_size * sizeof(float), stream);
  hipLaunchKernelGGL(hrsnn_decoder, dim3(256), dim3(256), 0, stream,
                     dpq, W1, b1, W2, b2, out);
}

// Round 9
// 491.484 us; speedup vs baseline: 1.7149x; 1.7149x over previous
//
#include <hip/hip_runtime.h>
#include <hip/hip_bf16.h>

// RiemannianGraph_HRSNN, MFMA version. B=2048, T=15, N=64. All I/O f32.
// R8 post-mortem: swizzle convicted (R8=R7-swizzle passed). But
// launch_bounds(512,4) capped regs at 128 -> VGPR 64 + spills (FETCH 1.86GB,
// 3.4TB/s scratch traffic) -> 650us. Conflict counter invariant 1.956e7
// across all layouts -> ~5% effect, not the lever.
// R9: (a) plain launch_bounds(512) (no waves clamp) + register shedding so
// 2 blocks/CU fit naturally: Ws2 frags -> LDS, Ll frags -> LDS (per-stripe),
// c2c/k1c/Xtf folded to per-step LDS broadcast reads. LDS 61312B.
// (b) decoder fast path: prep transposes+splits W1 into short W1h/W1l[col][k]
// at d_ws+32MiB (guarded by ws_size>=34MiB; fallback = proven R8 decoder).
//
// Math:
//   L 3-part x S1(exact)            -> 2^-27
//   M 3-part x Wg2 3-part (6 terms) -> ~2^-24
//   S1(exact) x Ws2 2-part          -> 2^-18 (no threshold downstream)
//   L 3-part x Xt 2-part (3 terms)  -> ~2^-17
//   dp 2-part x W1 2-part (3 terms) -> ~2^-16
// MFMA layouts: A[row=lane&15][k=8*(lane>>4)+j], B[k=8q+j][col=lane&15],
// C/D[row=4*(lane>>4)+reg][col=lane&15].

typedef __attribute__((ext_vector_type(8))) short s16x8;
typedef __attribute__((ext_vector_type(4))) float f32x4;
#define MFMA16(a, b, c) __builtin_amdgcn_mfma_f32_16x16x32_bf16(a, b, c, 0, 0, 0)

__device__ __forceinline__ short f2bs(float x) {
  union { __hip_bfloat16 h; short s; } u; u.h = __float2bfloat16(x); return u.s;
}
__device__ __forceinline__ float bs2f(short s) {
  union { short s; __hip_bfloat16 h; } u; u.s = s; return __bfloat162float(u.h);
}

#define LIF_STEP(mem, beta, thr, cur, spksum)                \
  {                                                          \
    float r_ = ((mem) > (thr)) ? (thr) : 0.0f;               \
    (mem) = (beta) * (mem) + (cur) - r_;                     \
    (spksum) += (((mem) - (thr)) > 0.0f) ? 1.0f : 0.0f;      \
  }

#define LFS 68      // Lf row stride (f32 words)
#define RS  36      // S1row / Mrow row stride
#define TS  65      // S1T row stride (odd -> conflict-free column pattern)

__global__ __launch_bounds__(512)
void hrsnn_main(const float* __restrict__ Lg,  const float* __restrict__ Xg,
                const float* __restrict__ Wp,  const float* __restrict__ bp,
                const float* __restrict__ Wg1, const float* __restrict__ bg1,
                const float* __restrict__ Ws1, const float* __restrict__ bs1,
                const float* __restrict__ Wg2, const float* __restrict__ bg2,
                const float* __restrict__ Ws2, const float* __restrict__ bs2,
                unsigned int* __restrict__ dp_out)
{
  // UBUF: union of Lf[64][68] (init only, 4352) with S1row[64][36]+Mrow[64][36]
  __shared__ __align__(16) float UBUF[4608];
  float* const Lf    = UBUF;          // init only
  float* const S1row = UBUF;          // [64][RS] plain row-major
  float* const Mrow  = UBUF + 2304;   // [64][RS] plain row-major
  __shared__ __align__(16) float S1T[32 * TS];          // S1 transposed [f][n]
  __shared__ __align__(16) short WgF[4 * 3 * 64 * 8];   // Wg2 frags [tile][part][lane][8]
  __shared__ __align__(16) short WsF[4 * 2 * 64 * 8];   // Ws2 frags [tile][part][lane][8]
  __shared__ __align__(16) short LlF[4 * 2 * 64 * 8];   // L low part  [p][slice][lane][8]
  __shared__ __align__(16) unsigned int XtHL[960];      // packed (hi<<16|lo) bf16 of Xt
  __shared__ float LxS[64], LsumS[64];
  __shared__ float u1A[32], cb1A[32], us1v[32], cs1v[32];
  __shared__ float u2gA[64], c2gA[64], u2sA[64], cs2A[64];

  const int tid = threadIdx.x;
  const int b = blockIdx.x;
  const int l = tid & 63, w = tid >> 6;
  const int p = w >> 1, h = w & 1;          // row-stripe / col-half
  const int q = l >> 4, c = l & 15;
  const int R = 16 * p;

  // ================= init 1: stage Lf, Xt (split), small weight folds ========
  const float* Lb = Lg + (size_t)b * 4096;
#pragma unroll
  for (int k = 0; k < 2; k++) {
    const int i4 = tid + 512 * k;                 // float4 index in [0,1024)
    const float4 v = *(const float4*)&Lb[i4 * 4];
    *(float4*)&Lf[(i4 >> 4) * LFS + (i4 & 15) * 4] = v;
  }
  const float* Xb = Xg + (size_t)b * 960;
  for (int i = tid; i < 960; i += 512) {
    const float x = Xb[i];
    const short hs = f2bs(x);
    const short ls = f2bs(x - bs2f(hs));
    XtHL[i] = ((unsigned int)(unsigned short)hs << 16) | (unsigned short)ls;
  }
  if (tid < 32) {
    const int f = tid;
    float a = 0.f, bb = 0.f, cc = 0.f, d = 0.f;
    for (int k = 0; k < 16; k++) {
      const float wp = Wp[k], bpv = bp[k];
      const float wg = Wg1[k * 32 + f], ws = Ws1[k * 32 + f];
      a += wp * wg; bb += bpv * wg;
      cc += wp * ws; d += bpv * ws;
    }
    u1A[f] = a; cb1A[f] = bb;
    us1v[f] = cc; cs1v[f] = d + bs1[f];
  }
  __syncthreads();

  // ================= init 2: Lsum, L A-frags, WgF, WsF =======================
  {
    const int n = tid >> 3, o = tid & 7;
    const float4 a4 = *(const float4*)&Lf[n * LFS + 8 * o];
    const float4 b4 = *(const float4*)&Lf[n * LFS + 8 * o + 4];
    float ps = a4.x + a4.y + a4.z + a4.w + b4.x + b4.y + b4.z + b4.w;
    ps += __shfl_xor(ps, 1, 64);
    ps += __shfl_xor(ps, 2, 64);
    ps += __shfl_xor(ps, 4, 64);
    if (o == 0) LsumS[n] = ps;
  }
  // L A-frags: Lh/Lm in regs; Ll stored to LDS (identical for h=0/1; h=0 stores)
  s16x8 Lh[2], Lm[2];
#pragma unroll
  for (int s = 0; s < 2; s++) {
    const float* rp = &Lf[(R + c) * LFS + 32 * s + 8 * q];
    const float4 v0 = *(const float4*)rp;
    const float4 v1 = *(const float4*)(rp + 4);
    float v[8] = {v0.x, v0.y, v0.z, v0.w, v1.x, v1.y, v1.z, v1.w};
    s16x8 fl;
#pragma unroll
    for (int j = 0; j < 8; j++) {
      const short hh = f2bs(v[j]);       const float r1 = v[j] - bs2f(hh);
      const short mm = f2bs(r1);         const float r2 = r1 - bs2f(mm);
      Lh[s][j] = hh; Lm[s][j] = mm; fl[j] = f2bs(r2);
    }
    if (h == 0) *(s16x8*)&LlF[((p * 2 + s) * 64 + l) * 8] = fl;
  }
  // Wg2 fragment store: wave w builds tile tt=w&3; w<4 -> parts 0,1; w>=4 -> part 2
  {
    const int tt = w & 3;
    float v[8];
#pragma unroll
    for (int j = 0; j < 8; j++) v[j] = Wg2[(8 * q + j) * 64 + 16 * tt + c];
    if (w < 4) {
      s16x8 fh, fm;
#pragma unroll
      for (int j = 0; j < 8; j++) {
        const short hh = f2bs(v[j]);
        fh[j] = hh; fm[j] = f2bs(v[j] - bs2f(hh));
      }
      *(s16x8*)&WgF[((tt * 3 + 0) * 64 + l) * 8] = fh;
      *(s16x8*)&WgF[((tt * 3 + 1) * 64 + l) * 8] = fm;
    } else {
      s16x8 fl;
#pragma unroll
      for (int j = 0; j < 8; j++) {
        const short hh = f2bs(v[j]);     const float r1 = v[j] - bs2f(hh);
        const short mm = f2bs(r1);       const float r2 = r1 - bs2f(mm);
        fl[j] = f2bs(r2);
      }
      *(s16x8*)&WgF[((tt * 3 + 2) * 64 + l) * 8] = fl;
    }
  }
  // Ws2 frags (2-part) -> LDS: wave w builds tile tw=w>>1, part pw=w&1
  {
    const int tw = w >> 1, pw = w & 1;
    s16x8 f;
#pragma unroll
    for (int j = 0; j < 8; j++) {
      const float x = Ws2[(8 * q + j) * 64 + 16 * tw + c];
      const short hh = f2bs(x);
      f[j] = pw ? f2bs(x - bs2f(hh)) : hh;
    }
    *(s16x8*)&WsF[((tw * 2 + pw) * 64 + l) * 8] = f;
  }
  __syncthreads();

  // ================= init 3: layer-2 derived vectors =========================
  if (tid < 64) {
    const int g = tid;
    float a = 0.f, bb = 0.f, cc = 0.f, d = 0.f;
    for (int f = 0; f < 32; f++) {
      const float wg = Wg2[f * 64 + g], ws = Ws2[f * 64 + g];
      a += us1v[f] * wg; bb += cs1v[f] * wg;
      cc += us1v[f] * ws; d += cs1v[f] * ws;
    }
    u2gA[g] = a; c2gA[g] = bb; u2sA[g] = cc; cs2A[g] = d + bs2[g];
  }
  __syncthreads();

  // ================= init 4: per-lane constants (registers only) =============
  float u2g2[2], u2s2[2], cs22[2], c2g2[2], bg22[2];
#pragma unroll
  for (int i = 0; i < 2; i++) {
    const int g = 32 * h + 16 * i + c;
    u2g2[i] = u2gA[g]; u2s2[i] = u2sA[g]; cs22[i] = cs2A[g];
    c2g2[i] = c2gA[g]; bg22[i] = bg2[g];
  }
  // LIF-1 mapping: f = tid&31, nb = tid>>5, cells n = nb + 16j
  const int f1 = tid & 31, nb = tid >> 5;
  const float u1f = u1A[f1], cb1f = cb1A[f1], bg1f = bg1[f1];

  // ================= state registers =========================================
  float m1a[4], m1n[4], m1m[4];
#pragma unroll
  for (int j = 0; j < 4; j++) { m1a[j] = 0.f; m1n[j] = 0.f; m1m[j] = 0.f; }
  float m2a[2][4], m2n[2][4], m2m[2][4], mli[2][4], dpa[2][4];
#pragma unroll
  for (int i = 0; i < 2; i++)
#pragma unroll
    for (int r = 0; r < 4; r++) {
      m2a[i][r] = 0.f; m2n[i][r] = 0.f; m2m[i][r] = 0.f;
      mli[i][r] = 0.f; dpa[i][r] = 0.f;
    }

  const f32x4 fz = {0.f, 0.f, 0.f, 0.f};
  __syncthreads();   // Lf dead; UBUF becomes S1row/Mrow

  // ================= time loop: 3 barriers/step ==============================
  // Barrier safety with no end-of-step barrier: D(t) reads Mrow; C(t+1)
  // writes Mrow only after alpha(t+1)+beta(t+1). Same two-barrier separation
  // covers C(t)'s S1row/S1T reads vs B(t+1)'s writes and B(t)'s LxS reads vs
  // A(t+1)'s writes. (Structure identical to R8, which passed.)
  for (int t = 0; t < 15; t++) {
    // ---- phase A: Lx = L@Xt via MFMA broadcast (all B-cols = Xt) ----
    f32x4 lx = fz;
#pragma unroll
    for (int s = 0; s < 2; s++) {
      const unsigned int* xw = &XtHL[t * 64 + 32 * s + 8 * q];
      const uint4 w0 = *(const uint4*)xw;
      const uint4 w1 = *(const uint4*)(xw + 4);
      unsigned int wv[8] = {w0.x, w0.y, w0.z, w0.w, w1.x, w1.y, w1.z, w1.w};
      s16x8 bh, bl;
#pragma unroll
      for (int j = 0; j < 8; j++) {
        bh[j] = (short)(wv[j] >> 16);
        bl[j] = (short)(wv[j] & 0xffff);
      }
      lx = MFMA16(Lh[s], bh, lx);
      lx = MFMA16(Lm[s], bh, lx);
      lx = MFMA16(Lh[s], bl, lx);
    }
    if (h == 0 && c == 0) {
#pragma unroll
      for (int r = 0; r < 4; r++) LxS[R + 4 * q + r] = lx[r];
    }
    __syncthreads();   // alpha

    // ---- phase B: layer-1 LIF -> S1row (plain) + S1T (transposed) ----
#pragma unroll
    for (int j = 0; j < 4; j++) {
      const int n = nb + 16 * j;
      const float cur = LxS[n] * u1f + LsumS[n] * cb1f + bg1f;
      float ss = 0.f;
      LIF_STEP(m1a[j], 0.8f, 0.8f, cur, ss);
      LIF_STEP(m1n[j], 0.9f, 1.0f, cur, ss);
      LIF_STEP(m1m[j], 0.95f, 1.5f, cur, ss);
      S1row[n * RS + f1] = ss;
      S1T[f1 * TS + n] = ss;
    }
    __syncthreads();   // beta

    // ---- phase C: M = L@S1 (3-part L, Ll from LDS), spk2d = S1@Ws2 ----
    f32x4 macc = fz;
#pragma unroll
    for (int s = 0; s < 2; s++) {
      s16x8 bS;
#pragma unroll
      for (int j = 0; j < 8; j++)
        bS[j] = f2bs(S1T[(16 * h + c) * TS + 32 * s + 8 * q + j]);
      const s16x8 LlS = *(const s16x8*)&LlF[((p * 2 + s) * 64 + l) * 8];
      macc = MFMA16(Lh[s], bS, macc);
      macc = MFMA16(Lm[s], bS, macc);
      macc = MFMA16(LlS, bS, macc);
    }
#pragma unroll
    for (int r = 0; r < 4; r++) Mrow[(R + 4 * q + r) * RS + 16 * h + c] = macc[r];

    f32x4 sacc[2];
    {
      const float* rp = &S1row[(R + c) * RS + 8 * q];
      const float4 v0 = *(const float4*)rp;
      const float4 v1 = *(const float4*)(rp + 4);
      const float v[8] = {v0.x, v0.y, v0.z, v0.w, v1.x, v1.y, v1.z, v1.w};
      s16x8 aS;
#pragma unroll
      for (int j = 0; j < 8; j++) aS[j] = f2bs(v[j]);
#pragma unroll
      for (int i = 0; i < 2; i++) {
        const int tw = 2 * h + i;
        const s16x8 WsH = *(const s16x8*)&WsF[((tw * 2 + 0) * 64 + l) * 8];
        const s16x8 WsL = *(const s16x8*)&WsF[((tw * 2 + 1) * 64 + l) * 8];
        sacc[i] = MFMA16(aS, WsH, fz);
        sacc[i] = MFMA16(aS, WsL, sacc[i]);
      }
    }
    __syncthreads();   // gamma

    // ---- phase D: cur2 = M@Wg2 (6-term) + LIF-2 (all in registers) ----
    s16x8 aMh, aMm, aMl;
    {
      const float* rp = &Mrow[(R + c) * RS + 8 * q];
      const float4 v0 = *(const float4*)rp;
      const float4 v1 = *(const float4*)(rp + 4);
      const float v[8] = {v0.x, v0.y, v0.z, v0.w, v1.x, v1.y, v1.z, v1.w};
#pragma unroll
      for (int j = 0; j < 8; j++) {
        const short hh = f2bs(v[j]);     const float r1 = v[j] - bs2f(hh);
        const short mm = f2bs(r1);       const float r2 = r1 - bs2f(mm);
        aMh[j] = hh; aMm[j] = mm; aMl[j] = f2bs(r2);
      }
    }
    float xtn[4], ls4[4];
#pragma unroll
    for (int r = 0; r < 4; r++) {
      const unsigned int xw = XtHL[t * 64 + R + 4 * q + r];
      xtn[r] = bs2f((short)(xw >> 16)) + bs2f((short)(xw & 0xffff));
      ls4[r] = LsumS[R + 4 * q + r];
    }

#pragma unroll
    for (int i = 0; i < 2; i++) {
      const int tt = 2 * h + i;
      const s16x8 bGh = *(const s16x8*)&WgF[((tt * 3 + 0) * 64 + l) * 8];
      const s16x8 bGm = *(const s16x8*)&WgF[((tt * 3 + 1) * 64 + l) * 8];
      const s16x8 bGl = *(const s16x8*)&WgF[((tt * 3 + 2) * 64 + l) * 8];
      f32x4 cacc = fz;
      cacc = MFMA16(aMh, bGh, cacc);
      cacc = MFMA16(aMh, bGm, cacc);
      cacc = MFMA16(aMm, bGh, cacc);
      cacc = MFMA16(aMh, bGl, cacc);
      cacc = MFMA16(aMm, bGm, cacc);
      cacc = MFMA16(aMl, bGh, cacc);
#pragma unroll
      for (int r = 0; r < 4; r++) {
        const float cur2 = cacc[r] + lx[r] * u2g2[i] + ls4[r] * c2g2[i] + bg22[i];
        float ss = 0.f;
        LIF_STEP(m2a[i][r], 0.8f, 0.8f, cur2, ss);
        LIF_STEP(m2n[i][r], 0.9f, 1.0f, cur2, ss);
        LIF_STEP(m2m[i][r], 0.95f, 1.5f, cur2, ss);
        const float spk2 = ss + sacc[i][r] + xtn[r] * u2s2[i] + cs22[i];
        mli[i][r] = 0.9f * mli[i][r] + spk2;
      }
    }
    if (t < 5) {
#pragma unroll
      for (int i = 0; i < 2; i++)
#pragma unroll
        for (int r = 0; r < 4; r++) dpa[i][r] -= mli[i][r];
    } else if (t >= 10) {
#pragma unroll
      for (int i = 0; i < 2; i++)
#pragma unroll
        for (int r = 0; r < 4; r++) dpa[i][r] += mli[i][r];
    }
    // no end-of-step barrier (see proof above)
  }

  // ---- dp_feat = (sum_last5 - sum_first5)/5, packed split-bf16 ----
  unsigned int* dpb = dp_out + (size_t)b * 4096;
#pragma unroll
  for (int i = 0; i < 2; i++) {
    const int g = 32 * h + 16 * i + c;
#pragma unroll
    for (int r = 0; r < 4; r++) {
      const int n = R + 4 * q + r;
      const float v = dpa[i][r] * 0.2f;
      const short hh = f2bs(v);
      const short ll = f2bs(v - bs2f(hh));
      dpb[n * 64 + g] = ((unsigned int)(unsigned short)hh << 16) | (unsigned short)ll;
    }
  }
}

// Prep: W1h/W1l[col][k] = split-bf16 of W1[k][col]. LDS tile transpose.
// grid 128 = 64 k-tiles x 2 col-tiles; coalesced both sides.
__global__ __launch_bounds__(256)
void hrsnn_prep(const float* __restrict__ W1,
                short* __restrict__ W1h, short* __restrict__ W1l)
{
  __shared__ unsigned int T[64][65];
  const int tid = threadIdx.x;
  const int k0 = (blockIdx.x >> 1) * 64, c0 = (blockIdx.x & 1) * 64;
#pragma unroll
  for (int pass = 0; pass < 16; pass++) {
    const int kk = pass * 4 + (tid >> 6);
    const int cc = tid & 63;
    const float x = W1[(size_t)(k0 + kk) * 128 + c0 + cc];
    const short hh = f2bs(x);
    const short ll = f2bs(x - bs2f(hh));
    T[kk][cc] = ((unsigned int)(unsigned short)hh << 16) | (unsigned short)ll;
  }
  __syncthreads();
#pragma unroll
  for (int pass = 0; pass < 16; pass++) {
    const int cc = pass * 4 + (tid >> 6);
    const int kk = tid & 63;
    const unsigned int wv = T[kk][cc];
    W1h[(size_t)(c0 + cc) * 4096 + k0 + kk] = (short)(wv >> 16);
    W1l[(size_t)(c0 + cc) * 4096 + k0 + kk] = (short)(wv & 0xffff);
  }
}

// Decoder fast path: out = relu(dp @ W1 + b1) @ W2 + b2, B-frags loaded
// directly from pre-split W1h/W1l (b128, zero in-loop split VALU).
// grid 256 = 128 batch-tiles x 2 col-halves; 4 waves = 4 col-tiles.
__global__ __launch_bounds__(256)
void hrsnn_decoder_fast(const unsigned int* __restrict__ dpq,
                        const short* __restrict__ W1h, const short* __restrict__ W1l,
                        const float* __restrict__ b1, const float* __restrict__ W2,
                        const float* __restrict__ b2, float* __restrict__ out)
{
  __shared__ __align__(16) float Hl[16][68];
  const int tid = threadIdx.x;
  const int l = tid & 63, tt = tid >> 6;
  const int q = l >> 4, c = l & 15;
  const int bt = blockIdx.x >> 1, ch = blockIdx.x & 1;
  const int colg = ch * 64 + tt * 16 + c;

  const unsigned int* ar = dpq + (size_t)(bt * 16 + c) * 4096 + 8 * q;
  const short* bh = W1h + (size_t)colg * 4096 + 8 * q;
  const short* bl = W1l + (size_t)colg * 4096 + 8 * q;

  const f32x4 fz = {0.f, 0.f, 0.f, 0.f};
  f32x4 acc0 = fz, acc1 = fz;
  for (int s = 0; s < 128; s += 2) {
#pragma unroll
    for (int u = 0; u < 2; u++) {
      const int su = s + u;
      const uint4 a0 = *(const uint4*)(ar + 32 * su);
      const uint4 a1 = *(const uint4*)(ar + 32 * su + 4);
      const unsigned int av[8] = {a0.x, a0.y, a0.z, a0.w, a1.x, a1.y, a1.z, a1.w};
      s16x8 Ah, Al;
#pragma unroll
      for (int j = 0; j < 8; j++) {
        Ah[j] = (short)(av[j] >> 16);
        Al[j] = (short)(av[j] & 0xffff);
      }
      const s16x8 Bh = *(const s16x8*)(bh + 32 * su);
      const s16x8 Bl = *(const s16x8*)(bl + 32 * su);
      if (u) {
        acc1 = MFMA16(Ah, Bh, acc1);
        acc1 = MFMA16(Al, Bh, acc1);
        acc1 = MFMA16(Ah, Bl, acc1);
      } else {
        acc0 = MFMA16(Ah, Bh, acc0);
        acc0 = MFMA16(Al, Bh, acc0);
        acc0 = MFMA16(Ah, Bl, acc0);
      }
    }
  }

  const float bk = b1[colg];
#pragma unroll
  for (int r = 0; r < 4; r++) {
    const float hv = acc0[r] + acc1[r] + bk;
    Hl[4 * q + r][tt * 16 + c] = hv > 0.f ? hv : 0.f;
  }
  __syncthreads();

  if (tid < 64) {
    const int i = tid >> 2, o = tid & 3;
    float s = (ch == 0) ? b2[o] : 0.f;
    for (int cc = 0; cc < 64; cc++)
      s += Hl[i][cc] * W2[(ch * 64 + cc) * 4 + o];
    atomicAdd(&out[(size_t)(bt * 16 + i) * 4 + o], s);
  }
}

// Fallback decoder (proven in R8): W1 staged per 128-row chunk in LDS.
__global__ __launch_bounds__(256, 4)
void hrsnn_decoder(const unsigned int* __restrict__ dpq,
                   const float* __restrict__ W1,
                   const float* __restrict__ b1, const float* __restrict__ W2,
                   const float* __restrict__ b2, float* __restrict__ out)
{
  __shared__ __align__(16) unsigned int T[128][65];
  __shared__ __align__(16) float Hl[16][68];
  const int tid = threadIdx.x;
  const int l = tid & 63, tt = tid >> 6;
  const int q = l >> 4, c = l & 15;
  const int bt = blockIdx.x >> 1, ch = blockIdx.x & 1;
  const int colg = ch * 64 + tt * 16 + c;

  const unsigned int* ar = dpq + (size_t)(bt * 16 + c) * 4096 + 8 * q;
  const float* wbase = W1 + ch * 64;

  const f32x4 fz = {0.f, 0.f, 0.f, 0.f};
  f32x4 acc0 = fz, acc1 = fz;
  for (int kc = 0; kc < 32; kc++) {
    __syncthreads();
#pragma unroll
    for (int u = 0; u < 8; u++) {
      const int i4 = tid + 256 * u;
      const int kk = i4 >> 4, c4 = (i4 & 15) * 4;
      const float4 v = *(const float4*)&wbase[(size_t)(kc * 128 + kk) * 128 + c4];
      const float vv[4] = {v.x, v.y, v.z, v.w};
#pragma unroll
      for (int e = 0; e < 4; e++) {
        const short hh = f2bs(vv[e]);
        const short ll = f2bs(vv[e] - bs2f(hh));
        T[kk][c4 + e] = ((unsigned int)(unsigned short)hh << 16) | (unsigned short)ll;
      }
    }
    __syncthreads();
#pragma unroll
    for (int sl = 0; sl < 4; sl++) {
      const int s = 4 * kc + sl;
      const uint4 a0 = *(const uint4*)(ar + 32 * s);
      const uint4 a1 = *(const uint4*)(ar + 32 * s + 4);
      const unsigned int av[8] = {a0.x, a0.y, a0.z, a0.w, a1.x, a1.y, a1.z, a1.w};
      s16x8 Ah, Al, Bh, Bl;
#pragma unroll
      for (int j = 0; j < 8; j++) {
        Ah[j] = (short)(av[j] >> 16);
        Al[j] = (short)(av[j] & 0xffff);
        const unsigned int bw = T[32 * sl + 8 * q + j][16 * tt + c];
        Bh[j] = (short)(bw >> 16);
        Bl[j] = (short)(bw & 0xffff);
      }
      if (sl & 1) {
        acc1 = MFMA16(Ah, Bh, acc1);
        acc1 = MFMA16(Al, Bh, acc1);
        acc1 = MFMA16(Ah, Bl, acc1);
      } else {
        acc0 = MFMA16(Ah, Bh, acc0);
        acc0 = MFMA16(Al, Bh, acc0);
        acc0 = MFMA16(Ah, Bl, acc0);
      }
    }
  }

  const float bk = b1[colg];
#pragma unroll
  for (int r = 0; r < 4; r++) {
    const float hv = acc0[r] + acc1[r] + bk;
    Hl[4 * q + r][tt * 16 + c] = hv > 0.f ? hv : 0.f;
  }
  __syncthreads();

  if (tid < 64) {
    const int i = tid >> 2, o = tid & 3;
    float s = (ch == 0) ? b2[o] : 0.f;
    for (int cc = 0; cc < 64; cc++)
      s += Hl[i][cc] * W2[(ch * 64 + cc) * 4 + o];
    atomicAdd(&out[(size_t)(bt * 16 + i) * 4 + o], s);
  }
}

extern "C" void kernel_launch(void* const* d_in, const int* in_sizes, int n_in,
                              void* d_out, int out_size, void* d_ws, size_t ws_size,
                              hipStream_t stream)
{
  const float* Lg  = (const float*)d_in[0];
  const float* Xg  = (const float*)d_in[1];
  const float* Wp  = (const float*)d_in[2];
  const float* bp  = (const float*)d_in[3];
  const float* Wg1 = (const float*)d_in[4];
  const float* bg1 = (const float*)d_in[5];
  const float* Ws1 = (const float*)d_in[6];
  const float* bs1 = (const float*)d_in[7];
  const float* Wg2 = (const float*)d_in[8];
  const float* bg2 = (const float*)d_in[9];
  const float* Ws2 = (const float*)d_in[10];
  const float* bs2 = (const float*)d_in[11];
  const float* W1  = (const float*)d_in[12];
  const float* b1  = (const float*)d_in[13];
  const float* W2  = (const float*)d_in[14];
  const float* b2  = (const float*)d_in[15];

  unsigned int* dpq = (unsigned int*)d_ws;           // 32 MiB
  const size_t DPQ = (size_t)2048 * 4096 * 4;
  const size_t W1T = (size_t)128 * 4096 * 2;         // 1 MiB each
  const bool fast = ws_size >= DPQ + 2 * W1T;        // static per harness
  short* W1h = (short*)((char*)d_ws + DPQ);
  short* W1l = (short*)((char*)d_ws + DPQ + W1T);
  float* out = (float*)d_out;

  if (fast)
    hipLaunchKernelGGL(hrsnn_prep, dim3(128), dim3(256), 0, stream, W1, W1h, W1l);
  hipLaunchKernelGGL(hrsnn_main, dim3(2048), dim3(512), 0, stream,
                     Lg, Xg, Wp, bp, Wg1, bg1, Ws1, bs1, Wg2, bg2, Ws2, bs2, dpq);
  hipMemsetAsync(d_out, 0, (size_t)out_size * sizeof(float), stream);
  if (fast)
    hipLaunchKernelGGL(hrsnn_decoder_fast, dim3(256), dim3(256), 0, stream,
                       dpq, W1h, W1l, b1, W2, b2, out);
  else
    hipLaunchKernelGGL(hrsnn_decoder, dim3(256), dim3(256), 0, stream,
                       dpq, W1, b1, W2, b2, out);
}